// Round 6
// baseline (1427.816 us; speedup 1.0000x reference)
//
#include <hip/hip_runtime.h>

// Problem constants
#define N_NODESC 50000
#define N_EDGESC 800000
#define EPSF 1e-5f
#define TILE_N 64
#define NTILE2 782                  // ceil(50000/64)
#define NKPAD  12544                // 49*256 >= 782*16
#define NKBLK  49
#define NEBLK  3125                 // 800000/256
#define PADV   (255 << 16)

typedef __attribute__((ext_vector_type(8))) short short8;
typedef __attribute__((ext_vector_type(16))) float f32x16;

// ---- ws layout (bytes) ----
#define WS_SCALE 0
#define WS_SHIFT 256
#define WS_BSUM  512
#define WS_PBUF  768                  // 782*128 f32
#define WS_HIST  401408               // 12544 int
#define WS_FILL  451584               // 12544 int
#define WS_SEG   501760               // 12800 int
#define WS_ELIST 552960               // 800000 int (src | dloc<<16)
#define WS_AHI   3752960              // 16*2*4*64*8 ushort = 128 KB
#define WS_ALO   3884032
#define WS_HB    4015104              // 50000*64 f32
#define WS_OUTB  16815104

__device__ __forceinline__ int edge_key(int d, int c) {
    return (d >> 6) * 16 + c;
}

// ---------------- preprocessing (unchanged, proven) ----------------
__global__ __launch_bounds__(256)
void k_hist(const int* __restrict__ src, const int* __restrict__ dst,
            const int* __restrict__ labels, const int* __restrict__ bidx,
            int* __restrict__ hist)
{
    const int e = blockIdx.x * 256 + threadIdx.x;
    if (e >= N_EDGESC) return;
    const int s = src[e], d = dst[e];
    const int c = (labels[d] * 2 + labels[s]) * 4 + bidx[e];
    atomicAdd(&hist[edge_key(d, c)], 1);
}

__global__ __launch_bounds__(256)
void k_bsum(const int* __restrict__ hist, int* __restrict__ bsum)
{
    __shared__ int s[256];
    const int i = blockIdx.x * 256 + threadIdx.x;
    s[threadIdx.x] = hist[i];
    __syncthreads();
    for (int off = 128; off > 0; off >>= 1) {
        if (threadIdx.x < off) s[threadIdx.x] += s[threadIdx.x + off];
        __syncthreads();
    }
    if (threadIdx.x == 0) bsum[blockIdx.x] = s[0];
}

__global__ void k_bscan(int* __restrict__ bsum)
{
    __shared__ int s[NKBLK];
    if (threadIdx.x < NKBLK) s[threadIdx.x] = bsum[threadIdx.x];
    __syncthreads();
    if (threadIdx.x == 0) {
        int run = 0;
        for (int i = 0; i < NKBLK; ++i) { const int v = s[i]; s[i] = run; run += v; }
    }
    __syncthreads();
    if (threadIdx.x < NKBLK) bsum[threadIdx.x] = s[threadIdx.x];
}

__global__ __launch_bounds__(256)
void k_escan(const int* __restrict__ hist, const int* __restrict__ bsum,
             int* __restrict__ seg)
{
    __shared__ int s[256];
    const int t = threadIdx.x;
    const int i = blockIdx.x * 256 + t;
    const int v = hist[i];
    s[t] = v; __syncthreads();
    for (int off = 1; off < 256; off <<= 1) {
        const int x = (t >= off) ? s[t - off] : 0;
        __syncthreads();
        s[t] += x;
        __syncthreads();
    }
    seg[i] = bsum[blockIdx.x] + s[t] - v;
}

__global__ __launch_bounds__(256)
void k_scat(const int* __restrict__ src, const int* __restrict__ dst,
            const int* __restrict__ labels, const int* __restrict__ bidx,
            const int* __restrict__ seg, int* __restrict__ fill,
            int* __restrict__ elist)
{
    const int e = blockIdx.x * 256 + threadIdx.x;
    if (e >= N_EDGESC) return;
    const int s = src[e], d = dst[e];
    const int c = (labels[d] * 2 + labels[s]) * 4 + bidx[e];
    const int k = edge_key(d, c);
    const int pos = seg[k] + atomicAdd(&fill[k], 1);
    elist[pos] = s | ((d & 63) << 16);
}

// ---- precompute MFMA A-fragments (split bf16 hi/lo), layout verified in R5 ----
__global__ void k_mfrag(const float* __restrict__ M, ushort* __restrict__ Ahi,
                        ushort* __restrict__ Alo)
{
    const int c = blockIdx.x;
    for (int slot = threadIdx.x; slot < 512; slot += 256) {
        const int t = slot >> 8, s = (slot >> 6) & 3, lane = slot & 63;
        const int row = (lane & 31) + 32 * t;
        const int kb = 16 * s + 8 * (lane >> 5);
        const int fid = ((c * 2 + t) * 4 + s) * 64 + lane;
#pragma unroll
        for (int j = 0; j < 8; ++j) {
            const float v = M[c * 4096 + row * 64 + kb + j];
            const unsigned b = __float_as_uint(v);
            const float lof = v - __uint_as_float(b & 0xFFFF0000u);
            Ahi[fid * 8 + j] = (ushort)(b >> 16);
            Alo[fid * 8 + j] = (ushort)(__float_as_uint(lof) >> 16);
        }
    }
}

// ---------------- h = in @ W + b ----------------
__global__ __launch_bounds__(256)
void k_h(const float* __restrict__ in, const float* __restrict__ W,
         const float* __restrict__ b, float* __restrict__ h, const int F)
{
    const int t = blockIdx.x * 256 + threadIdx.x;
    if (t >= N_NODESC * 64) return;
    const int n = t >> 6, e = t & 63;
    const float* __restrict__ xr = in + (long)n * F;
    float acc = b[e];
    for (int f = 0; f < F; f += 4) {
        acc += xr[f]     * W[f * 64 + e];
        acc += xr[f + 1] * W[(f + 1) * 64 + e];
        acc += xr[f + 2] * W[(f + 2) * 64 + e];
        acc += xr[f + 3] * W[(f + 3) * 64 + e];
    }
    h[t] = acc;
}

// ---------------- fused LN-apply + relu + next-layer GEMM ----------------
__global__ __launch_bounds__(256)
void k_happly(const float* __restrict__ outb, const float* __restrict__ scale,
              const float* __restrict__ shift, const float* __restrict__ W,
              const float* __restrict__ b, float* __restrict__ h)
{
    __shared__ float act[4][64];
    const int nl = threadIdx.x >> 6, o = threadIdx.x & 63;
    const int n = blockIdx.x * 4 + nl;
    const float v = outb[(long)n * 64 + o] * scale[o] + shift[o];
    act[nl][o] = fmaxf(v, 0.f);
    __syncthreads();
    float a = b[o];
#pragma unroll 16
    for (int f = 0; f < 64; ++f) a += act[nl][f] * W[f * 64 + o];
    h[(long)n * 64 + o] = a;
}

// ---------------- MFMA edge transform: coalesced gather + LDS staging ----------
// One block per 64-dst tile; wave w handles combos w, w+4, w+8, w+12.
// Per 32-edge group: coalesced fp32 h gathers (1 line / 4 lanes), in-register
// split to bf16 hi/lo, ds_write into B-frag layout, 24 MFMA (A reloaded from
// L2-hot table per K-step), LDS float-atomic scatter by dst-local.
// Depth-2 pipeline: next group's elist + gathers issued before current MFMA.
__global__ __launch_bounds__(256)
void k_msgT(const float* __restrict__ h, const int* __restrict__ elist,
            const int* __restrict__ seg, const ushort* __restrict__ Ahi,
            const ushort* __restrict__ Alo, float* __restrict__ outb,
            float* __restrict__ pbuf)
{
    __shared__ float acc[TILE_N * 65];                 // 16.6 KB
    __shared__ ushort HB[4][2][2048];                  // 32 KB: [wave][hi/lo][s2*256+edge*8]
    __shared__ float rsum[4][64], rsq[4][64];
    const int tid = threadIdx.x;
    const int w = tid >> 6, lane = tid & 63;
    const int col = lane & 31, hig = lane >> 5;
    const int jr_base = lane >> 2, qlo = lane & 3;
    const int tile = blockIdx.x;
    const float4* __restrict__ h4 = (const float4*)h;

    for (int i = tid; i < TILE_N * 65; i += 256) acc[i] = 0.f;
    __syncthreads();

    for (int ci = 0; ci < 4; ++ci) {
        const int c = w + 4 * ci;
        const int s0 = seg[tile * 16 + c];
        const int s1 = seg[tile * 16 + c + 1];
        if (s0 >= s1) continue;

        // ---- prologue: group-0 elist + gathers, group-1 elist ----
        int ep_cur = (s0 + col < s1) ? elist[s0 + col] : PADV;
        float4 g[8];
#pragma unroll
        for (int r = 0; r < 8; ++r) {
            const int jr = 16 * (r & 1) + jr_base;
            const int qr = qlo + 4 * (r >> 1);
            const int sj = __shfl(ep_cur, jr) & 0xFFFF;
            g[r] = h4[sj * 16 + qr];
        }
        int ep_nxt = (s0 + 32 + col < s1) ? elist[s0 + 32 + col] : PADV;

        for (int p = s0; p < s1; p += 32) {
            // ---- 1. convert current gathers to split-bf16, stage in LDS ----
#pragma unroll
            for (int r = 0; r < 8; ++r) {
                const float4 v = g[r];
                const unsigned bx = __float_as_uint(v.x), by = __float_as_uint(v.y);
                const unsigned bz = __float_as_uint(v.z), bw = __float_as_uint(v.w);
                uint2 hiw, low;
                hiw.x = (bx >> 16) | (by & 0xFFFF0000u);
                hiw.y = (bz >> 16) | (bw & 0xFFFF0000u);
                const float lx = v.x - __uint_as_float(bx & 0xFFFF0000u);
                const float ly = v.y - __uint_as_float(by & 0xFFFF0000u);
                const float lz = v.z - __uint_as_float(bz & 0xFFFF0000u);
                const float lw = v.w - __uint_as_float(bw & 0xFFFF0000u);
                low.x = (__float_as_uint(lx) >> 16) | (__float_as_uint(ly) & 0xFFFF0000u);
                low.y = (__float_as_uint(lz) >> 16) | (__float_as_uint(lw) & 0xFFFF0000u);
                const int jr = 16 * (r & 1) + jr_base;
                const int qr = qlo + 4 * (r >> 1);
                const int off = (qr >> 1) * 256 + jr * 8 + (qr & 1) * 4;
                *(uint2*)&HB[w][0][off] = hiw;
                *(uint2*)&HB[w][1][off] = low;
            }

            // ---- 2. issue next group's gathers (stay in flight through MFMA) ----
            const int ep_hold = ep_cur;
            if (p + 32 < s1) {
                ep_cur = ep_nxt;
#pragma unroll
                for (int r = 0; r < 8; ++r) {
                    const int jr = 16 * (r & 1) + jr_base;
                    const int qr = qlo + 4 * (r >> 1);
                    const int sj = __shfl(ep_cur, jr) & 0xFFFF;
                    g[r] = h4[sj * 16 + qr];
                }
                ep_nxt = (p + 64 + col < s1) ? elist[p + 64 + col] : PADV;
            }

            // ---- 3. MFMA: B from LDS, A reloaded from L2-hot table ----
            f32x16 c0, c1;
#pragma unroll
            for (int i = 0; i < 16; ++i) { c0[i] = 0.f; c1[i] = 0.f; }
#pragma unroll
            for (int s = 0; s < 4; ++s) {
                const int fid = ((c * 2) * 4 + s) * 64 + lane;
                const short8 a0h = *(const short8*)&Ahi[fid * 8];
                const short8 a1h = *(const short8*)&Ahi[(fid + 256) * 8];
                const short8 a0l = *(const short8*)&Alo[fid * 8];
                const short8 a1l = *(const short8*)&Alo[(fid + 256) * 8];
                const int boff = ((s << 1) | hig) * 256 + col * 8;
                const short8 bh = *(const short8*)&HB[w][0][boff];
                const short8 bl = *(const short8*)&HB[w][1][boff];
                c0 = __builtin_amdgcn_mfma_f32_32x32x16_bf16(a0h, bh, c0, 0, 0, 0);
                c1 = __builtin_amdgcn_mfma_f32_32x32x16_bf16(a1h, bh, c1, 0, 0, 0);
                c0 = __builtin_amdgcn_mfma_f32_32x32x16_bf16(a0h, bl, c0, 0, 0, 0);
                c1 = __builtin_amdgcn_mfma_f32_32x32x16_bf16(a1h, bl, c1, 0, 0, 0);
                c0 = __builtin_amdgcn_mfma_f32_32x32x16_bf16(a0l, bh, c0, 0, 0, 0);
                c1 = __builtin_amdgcn_mfma_f32_32x32x16_bf16(a1l, bh, c1, 0, 0, 0);
            }

            // ---- 4. LDS float-atomic scatter (C layout verified R5) ----
            const int dl = ep_hold >> 16;
            if (dl < 64) {
                const int base = dl * 65 + 4 * hig;
#pragma unroll
                for (int r = 0; r < 16; ++r) {
                    const int fp = (r & 3) + 8 * (r >> 2);
                    atomicAdd(&acc[base + fp], c0[r]);
                    atomicAdd(&acc[base + fp + 32], c1[r]);
                }
            }
        }
    }
    __syncthreads();

    // ---- epilogue: residual + store + LN partials ----
    const int o = lane;
    float s1v = 0.f, s2v = 0.f;
#pragma unroll
    for (int i = 0; i < 16; ++i) {
        const int d = w * 16 + i;
        const int gd = tile * TILE_N + d;
        if (gd < N_NODESC) {
            const float v = acc[d * 65 + o] + h[(long)gd * 64 + o];
            outb[(long)gd * 64 + o] = v;
            s1v += v; s2v += v * v;
        }
    }
    rsum[w][o] = s1v; rsq[w][o] = s2v;
    __syncthreads();
    if (tid < 64) {
        float t1 = 0.f, t2 = 0.f;
#pragma unroll
        for (int k = 0; k < 4; ++k) { t1 += rsum[k][tid]; t2 += rsq[k][tid]; }
        pbuf[tile * 128 + tid] = t1;
        pbuf[tile * 128 + 64 + tid] = t2;
    }
}

// ---------------- reduce LN partials -> scale/shift ----------------
__global__ __launch_bounds__(1024)
void k_norm2(const float* __restrict__ pbuf, const float* __restrict__ g,
             const float* __restrict__ be, float* __restrict__ scale,
             float* __restrict__ shift)
{
    __shared__ float s[1024];
    const int t = threadIdx.x, j = t & 127, gg = t >> 7;
    float a = 0.f;
    for (int b = gg; b < NTILE2; b += 8) a += pbuf[b * 128 + j];
    s[t] = a;
    __syncthreads();
    if (t < 128) {
        float tot = 0.f;
#pragma unroll
        for (int k = 0; k < 8; ++k) tot += s[j + 128 * k];
        s[t] = tot;
    }
    __syncthreads();
    if (t < 64) {
        const double mu  = (double)s[t] / (double)N_NODESC;
        const double var = (double)s[64 + t] / (double)N_NODESC - mu * mu;
        const double sc  = (double)g[t] / sqrt(var + (double)EPSF);
        scale[t] = (float)sc;
        shift[t] = (float)((double)be[t] - mu * sc);
    }
}

// ---------------- final projection (LN apply fused) ----------------
__global__ __launch_bounds__(256)
void k_out(const float* __restrict__ outb, const float* __restrict__ scale,
           const float* __restrict__ shift, const float* __restrict__ resW,
           const float* __restrict__ resb, float* __restrict__ out)
{
    const int n = blockIdx.x * 256 + threadIdx.x;
    if (n >= N_NODESC) return;
    float a0 = resb[0], a1 = resb[1];
    const float* __restrict__ r = outb + (long)n * 64;
#pragma unroll 8
    for (int e = 0; e < 64; ++e) {
        const float v = fmaxf(r[e] * scale[e] + shift[e], 0.f);
        a0 += v * resW[2 * e];
        a1 += v * resW[2 * e + 1];
    }
    out[2 * n] = a0;
    out[2 * n + 1] = a1;
}

extern "C" void kernel_launch(void* const* d_in, const int* in_sizes, int n_in,
                              void* d_out, int out_size, void* d_ws, size_t ws_size,
                              hipStream_t stream)
{
    const float* x      = (const float*)d_in[0];
    const float* M      = (const float*)d_in[1];
    const int*   src    = (const int*)d_in[2];
    const int*   dst    = (const int*)d_in[3];
    const int*   labels = (const int*)d_in[4];
    const int*   bidx   = (const int*)d_in[5];
    const float* resW   = (const float*)d_in[18];
    const float* resb   = (const float*)d_in[19];
    float* out = (float*)d_out;

    char* ws = (char*)d_ws;
    float*  scale = (float*)(ws + WS_SCALE);
    float*  shift = (float*)(ws + WS_SHIFT);
    int*    bsum  = (int*)(ws + WS_BSUM);
    float*  pbuf  = (float*)(ws + WS_PBUF);
    int*    hist  = (int*)(ws + WS_HIST);
    int*    fill  = (int*)(ws + WS_FILL);
    int*    seg   = (int*)(ws + WS_SEG);
    int*    elist = (int*)(ws + WS_ELIST);
    ushort* Ahi   = (ushort*)(ws + WS_AHI);
    ushort* Alo   = (ushort*)(ws + WS_ALO);
    float*  hB    = (float*)(ws + WS_HB);
    float*  outb  = (float*)(ws + WS_OUTB);

    const int NB64 = (N_NODESC * 64 + 255) / 256;  // 12500

    // ---- preprocessing (graph + M constant across layers) ----
    hipMemsetAsync(hist, 0, 2 * NKPAD * sizeof(int), stream);   // hist + fill
    k_hist<<<NEBLK, 256, 0, stream>>>(src, dst, labels, bidx, hist);
    k_bsum<<<NKBLK, 256, 0, stream>>>(hist, bsum);
    k_bscan<<<1, 64, 0, stream>>>(bsum);
    k_escan<<<NKBLK, 256, 0, stream>>>(hist, bsum, seg);
    k_scat<<<NEBLK, 256, 0, stream>>>(src, dst, labels, bidx, seg, fill, elist);
    k_mfrag<<<16, 256, 0, stream>>>(M, Ahi, Alo);

    for (int l = 0; l < 3; ++l) {
        const float* W  = (const float*)d_in[6 + 4 * l];
        const float* b  = (const float*)d_in[7 + 4 * l];
        const float* g  = (const float*)d_in[8 + 4 * l];
        const float* be = (const float*)d_in[9 + 4 * l];

        if (l == 0) {
            k_h<<<NB64, 256, 0, stream>>>(x, W, b, hB, 128);
        } else {
            k_happly<<<N_NODESC / 4, 256, 0, stream>>>(outb, scale, shift, W, b, hB);
        }
        k_msgT<<<NTILE2, 256, 0, stream>>>(hB, elist, seg, Ahi, Alo, outb, pbuf);
        k_norm2<<<1, 1024, 0, stream>>>(pbuf, g, be, scale, shift);
    }
    k_out<<<(N_NODESC + 255) / 256, 256, 0, stream>>>(outb, scale, shift, resW, resb, out);
    (void)in_sizes; (void)n_in; (void)out_size; (void)ws_size;
}

// Round 8
// 646.063 us; speedup vs baseline: 2.2100x; 2.2100x over previous
//
#include <hip/hip_runtime.h>

// Problem constants
#define N_NODESC 50000
#define N_EDGESC 800000
#define EPSF 1e-5f
#define NTILE 782                   // ceil(50000/64)
#define NKEYS 800768                // 3128*256 = NTILE*4*256 (full tile range!)
#define NHBLK 3128
#define NEBLK 3125                  // 800000/256

typedef __attribute__((ext_vector_type(8))) short short8;
typedef __attribute__((ext_vector_type(16))) float f32x16;

// ---- ws layout (bytes), total ~51.9 MB ----
#define WS_SCALE 0
#define WS_SHIFT 256
#define WS_BSUM  512                  // 3128 int
#define WS_PBUF  13056                // 782*128 f32
#define WS_HIST  413440               // 800768 int
#define WS_FILL  3616512              // 800768 int (contiguous after hist)
#define WS_SEG   6819584              // 800769 int
#define WS_ELIST 10022720             // 800000 int (src only)
#define WS_AHI   13222720             // 128 KB
#define WS_ALO   13353792             // 128 KB
#define WS_HHI   13484864             // 50000*64 ushort
#define WS_HLO   19884864
#define WS_HB    26284864             // 50000*64 f32
#define WS_OUTB  39084864

// key = (tile64, dlq, combo, dl) ; (d>>4) = tile*4 + dlq
__device__ __forceinline__ int edge_key(int d, int c) {
    return (d >> 4) * 256 + c * 16 + (d & 15);
}

// ---------------- histogram ----------------
__global__ __launch_bounds__(256)
void k_hist(const int* __restrict__ src, const int* __restrict__ dst,
            const int* __restrict__ labels, const int* __restrict__ bidx,
            int* __restrict__ hist)
{
    const int e = blockIdx.x * 256 + threadIdx.x;
    if (e >= N_EDGESC) return;
    const int s = src[e], d = dst[e];
    const int c = (labels[d] * 2 + labels[s]) * 4 + bidx[e];
    atomicAdd(&hist[edge_key(d, c)], 1);
}

// ---------------- 3-level scan ----------------
__global__ __launch_bounds__(256)
void k_bsum(const int* __restrict__ hist, int* __restrict__ bsum)
{
    __shared__ int s[256];
    const int i = blockIdx.x * 256 + threadIdx.x;
    s[threadIdx.x] = hist[i];
    __syncthreads();
    for (int off = 128; off > 0; off >>= 1) {
        if (threadIdx.x < off) s[threadIdx.x] += s[threadIdx.x + off];
        __syncthreads();
    }
    if (threadIdx.x == 0) bsum[blockIdx.x] = s[0];
}

__global__ __launch_bounds__(1024)
void k_bscan2(int* __restrict__ bsum)   // in-place exclusive scan of NHBLK entries
{
    __shared__ int s[1024];
    const int t = threadIdx.x;
    int v[4]; int tot = 0;
#pragma unroll
    for (int j = 0; j < 4; ++j) {
        const int i = t * 4 + j;
        v[j] = (i < NHBLK) ? bsum[i] : 0;
        tot += v[j];
    }
    s[t] = tot; __syncthreads();
    for (int off = 1; off < 1024; off <<= 1) {
        const int x = (t >= off) ? s[t - off] : 0;
        __syncthreads();
        s[t] += x;
        __syncthreads();
    }
    int base = s[t] - tot;
#pragma unroll
    for (int j = 0; j < 4; ++j) {
        const int i = t * 4 + j;
        if (i < NHBLK) bsum[i] = base;
        base += v[j];
    }
}

__global__ __launch_bounds__(256)
void k_escan2(const int* __restrict__ hist, const int* __restrict__ bsum,
              int* __restrict__ seg)
{
    __shared__ int s[256];
    const int t = threadIdx.x;
    const int i = blockIdx.x * 256 + t;
    const int v = hist[i];
    s[t] = v; __syncthreads();
    for (int off = 1; off < 256; off <<= 1) {
        const int x = (t >= off) ? s[t - off] : 0;
        __syncthreads();
        s[t] += x;
        __syncthreads();
    }
    const int incl = s[t];
    seg[i] = bsum[blockIdx.x] + incl - v;
    if (i == NKEYS - 1) seg[NKEYS] = bsum[blockIdx.x] + incl;
}

__global__ __launch_bounds__(256)
void k_scat(const int* __restrict__ src, const int* __restrict__ dst,
            const int* __restrict__ labels, const int* __restrict__ bidx,
            const int* __restrict__ seg, int* __restrict__ fill,
            int* __restrict__ elist)
{
    const int e = blockIdx.x * 256 + threadIdx.x;
    if (e >= N_EDGESC) return;
    const int s = src[e], d = dst[e];
    const int c = (labels[d] * 2 + labels[s]) * 4 + bidx[e];
    const int k = edge_key(d, c);
    const int pos = seg[k] + atomicAdd(&fill[k], 1);
    elist[pos] = s;
}

// ---- MFMA A-fragments (split bf16 hi/lo), layout verified R5 ----
__global__ void k_mfrag(const float* __restrict__ M, ushort* __restrict__ Ahi,
                        ushort* __restrict__ Alo)
{
    const int c = blockIdx.x;
    for (int slot = threadIdx.x; slot < 512; slot += 256) {
        const int t = slot >> 8, s = (slot >> 6) & 3, lane = slot & 63;
        const int row = (lane & 31) + 32 * t;
        const int kb = 16 * s + 8 * (lane >> 5);
        const int fid = ((c * 2 + t) * 4 + s) * 64 + lane;
#pragma unroll
        for (int j = 0; j < 8; ++j) {
            const float v = M[c * 4096 + row * 64 + kb + j];
            const unsigned b = __float_as_uint(v);
            const float lof = v - __uint_as_float(b & 0xFFFF0000u);
            Ahi[fid * 8 + j] = (ushort)(b >> 16);
            Alo[fid * 8 + j] = (ushort)(__float_as_uint(lof) >> 16);
        }
    }
}

// ---------------- h = in @ W + b, + split-bf16 outputs ----------------
__global__ __launch_bounds__(256)
void k_h(const float* __restrict__ in, const float* __restrict__ W,
         const float* __restrict__ b, float* __restrict__ h,
         ushort* __restrict__ hhi, ushort* __restrict__ hlo, const int F)
{
    const int t = blockIdx.x * 256 + threadIdx.x;
    if (t >= N_NODESC * 64) return;
    const int n = t >> 6, e = t & 63;
    const float* __restrict__ xr = in + (long)n * F;
    float acc = b[e];
    for (int f = 0; f < F; f += 4) {
        acc += xr[f]     * W[f * 64 + e];
        acc += xr[f + 1] * W[(f + 1) * 64 + e];
        acc += xr[f + 2] * W[(f + 2) * 64 + e];
        acc += xr[f + 3] * W[(f + 3) * 64 + e];
    }
    h[t] = acc;
    const unsigned bb = __float_as_uint(acc);
    const float lof = acc - __uint_as_float(bb & 0xFFFF0000u);
    hhi[t] = (ushort)(bb >> 16);
    hlo[t] = (ushort)(__float_as_uint(lof) >> 16);
}

// ---------------- fused LN-apply + relu + next-layer GEMM + split -----------
__global__ __launch_bounds__(256)
void k_happly(const float* __restrict__ outb, const float* __restrict__ scale,
              const float* __restrict__ shift, const float* __restrict__ W,
              const float* __restrict__ b, float* __restrict__ h,
              ushort* __restrict__ hhi, ushort* __restrict__ hlo)
{
    __shared__ float act[4][64];
    const int nl = threadIdx.x >> 6, o = threadIdx.x & 63;
    const int n = blockIdx.x * 4 + nl;
    const float v = outb[(long)n * 64 + o] * scale[o] + shift[o];
    act[nl][o] = fmaxf(v, 0.f);
    __syncthreads();
    float a = b[o];
#pragma unroll 16
    for (int f = 0; f < 64; ++f) a += act[nl][f] * W[f * 64 + o];
    const long t = (long)n * 64 + o;
    h[t] = a;
    const unsigned bb = __float_as_uint(a);
    const float lof = a - __uint_as_float(bb & 0xFFFF0000u);
    hhi[t] = (ushort)(bb >> 16);
    hlo[t] = (ushort)(__float_as_uint(lof) >> 16);
}

// ---------------- MFMA transform + register aggregation (NO atomics) --------
// Block = 64-dst tile; wave w owns dst rows [16w,16w+16) for ALL 16 combos.
// Per 32-edge chunk: MFMA -> ds_write msg tile (per-wave, swizzled) ->
// wave-local segment-sum into register acc (lane = (dl, featquad)).
__global__ __launch_bounds__(256, 3)
void k_msgF(const ushort* __restrict__ hhi, const ushort* __restrict__ hlo,
            const float* __restrict__ hres, const int* __restrict__ elist,
            const int* __restrict__ seg, const ushort* __restrict__ Ahi,
            const ushort* __restrict__ Alo, float* __restrict__ outb,
            float* __restrict__ pbuf)
{
    __shared__ float msg[4][2048];        // per-wave 32 edges x 64 feats (8 KB)
    __shared__ float red[2][4][64];
    const int tid = threadIdx.x;
    const int w = tid >> 6, lane = tid & 63;
    const int col = lane & 31, hig = lane >> 5;     // MFMA roles
    const int dl = lane >> 2, fq = lane & 3;        // reduce roles
    const int tile = blockIdx.x;
    const int kbase = (tile * 4 + w) * 256;
    float* __restrict__ msgw = msg[w];

    float4 a0 = {0,0,0,0}, a1 = a0, a2 = a0, a3 = a0;

    for (int c = 0; c < 16; ++c) {
        const int S0 = seg[kbase + c * 16];
        const int S1 = seg[kbase + c * 16 + 16];
        if (S0 >= S1) continue;
        const int rlo = seg[kbase + c * 16 + dl];
        const int rhi = seg[kbase + c * 16 + dl + 1];

        for (int p = S0; p < S1; p += 32) {
            const int idx = p + col;
            const int srcn = elist[(idx < S1) ? idx : (S1 - 1)];

            // B fragments directly from split tables (pattern verified R5)
            const ushort* __restrict__ rh = hhi + srcn * 64 + hig * 8;
            const ushort* __restrict__ rl = hlo + srcn * 64 + hig * 8;
            short8 bh[4], bl[4];
#pragma unroll
            for (int s = 0; s < 4; ++s) {
                bh[s] = *(const short8*)&rh[s * 16];
                bl[s] = *(const short8*)&rl[s * 16];
            }

            f32x16 c0, c1;
#pragma unroll
            for (int i = 0; i < 16; ++i) { c0[i] = 0.f; c1[i] = 0.f; }
#pragma unroll
            for (int s = 0; s < 4; ++s) {
                const int fidb = (c * 8 + s) * 64 + lane;
                const short8 a0h = *(const short8*)&Ahi[fidb * 8];
                const short8 a1h = *(const short8*)&Ahi[(fidb + 256) * 8];
                const short8 a0l = *(const short8*)&Alo[fidb * 8];
                const short8 a1l = *(const short8*)&Alo[(fidb + 256) * 8];
                c0 = __builtin_amdgcn_mfma_f32_32x32x16_bf16(a0h, bh[s], c0, 0, 0, 0);
                c1 = __builtin_amdgcn_mfma_f32_32x32x16_bf16(a1h, bh[s], c1, 0, 0, 0);
                c0 = __builtin_amdgcn_mfma_f32_32x32x16_bf16(a0h, bl[s], c0, 0, 0, 0);
                c1 = __builtin_amdgcn_mfma_f32_32x32x16_bf16(a1h, bl[s], c1, 0, 0, 0);
                c0 = __builtin_amdgcn_mfma_f32_32x32x16_bf16(a0l, bh[s], c0, 0, 0, 0);
                c1 = __builtin_amdgcn_mfma_f32_32x32x16_bf16(a1l, bh[s], c1, 0, 0, 0);
            }

            // stage message tile: msg[col][feat], feat XOR-swizzled (<=4-way banks)
            const int sw = (col & 7) << 3;
            const int cb = col * 64;
#pragma unroll
            for (int rq = 0; rq < 4; ++rq) {
                const int fb = 8 * rq + 4 * hig;     // C row = (r&3)+8(r>>2)+4hig
                float4 v0 = {c0[4*rq], c0[4*rq+1], c0[4*rq+2], c0[4*rq+3]};
                float4 v1 = {c1[4*rq], c1[4*rq+1], c1[4*rq+2], c1[4*rq+3]};
                *(float4*)&msgw[cb + (fb ^ sw)] = v0;
                *(float4*)&msgw[cb + ((fb + 32) ^ sw)] = v1;
            }
            asm volatile("s_waitcnt lgkmcnt(0)" ::: "memory");

            // wave-local segmented sum: lane (dl,fq) sums its dl's column range
            const int lo = max(rlo - p, 0);
            const int hi = min(rhi - p, 32);
            for (int q = lo; q < hi; ++q) {
                const int qs = (q & 7) << 3;
                const int qb = q * 64;
                const float4 v0 = *(const float4*)&msgw[qb + ((16*fq + 0) ^ qs)];
                const float4 v1 = *(const float4*)&msgw[qb + ((16*fq + 4) ^ qs)];
                const float4 v2 = *(const float4*)&msgw[qb + ((16*fq + 8) ^ qs)];
                const float4 v3 = *(const float4*)&msgw[qb + ((16*fq + 12) ^ qs)];
                a0.x += v0.x; a0.y += v0.y; a0.z += v0.z; a0.w += v0.w;
                a1.x += v1.x; a1.y += v1.y; a1.z += v1.z; a1.w += v1.w;
                a2.x += v2.x; a2.y += v2.y; a2.z += v2.z; a2.w += v2.w;
                a3.x += v3.x; a3.y += v3.y; a3.z += v3.z; a3.w += v3.w;
            }
            asm volatile("s_waitcnt lgkmcnt(0)" ::: "memory");
        }
    }

    // ---- epilogue: residual + store + LN partials (shfl over dl lanes) ----
    const int gd = tile * 64 + w * 16 + dl;
    float4 v[4] = {a0, a1, a2, a3};
    if (gd < N_NODESC) {
        const float4* __restrict__ hr = (const float4*)(hres + (long)gd * 64 + 16 * fq);
        float4* __restrict__ ob = (float4*)(outb + (long)gd * 64 + 16 * fq);
#pragma unroll
        for (int u = 0; u < 4; ++u) {
            const float4 r = hr[u];
            v[u].x += r.x; v[u].y += r.y; v[u].z += r.z; v[u].w += r.w;
            ob[u] = v[u];
        }
    } else {
#pragma unroll
        for (int u = 0; u < 4; ++u) v[u] = make_float4(0.f, 0.f, 0.f, 0.f);
    }
    float s1[16], s2[16];
#pragma unroll
    for (int u = 0; u < 4; ++u) {
        s1[4*u+0] = v[u].x; s2[4*u+0] = v[u].x * v[u].x;
        s1[4*u+1] = v[u].y; s2[4*u+1] = v[u].y * v[u].y;
        s1[4*u+2] = v[u].z; s2[4*u+2] = v[u].z * v[u].z;
        s1[4*u+3] = v[u].w; s2[4*u+3] = v[u].w * v[u].w;
    }
#pragma unroll
    for (int j = 0; j < 16; ++j) {
        s1[j] += __shfl_xor(s1[j], 4);  s2[j] += __shfl_xor(s2[j], 4);
        s1[j] += __shfl_xor(s1[j], 8);  s2[j] += __shfl_xor(s2[j], 8);
        s1[j] += __shfl_xor(s1[j], 16); s2[j] += __shfl_xor(s2[j], 16);
        s1[j] += __shfl_xor(s1[j], 32); s2[j] += __shfl_xor(s2[j], 32);
    }
    if (dl == 0) {
#pragma unroll
        for (int j = 0; j < 16; ++j) {
            red[0][w][16 * fq + j] = s1[j];
            red[1][w][16 * fq + j] = s2[j];
        }
    }
    __syncthreads();
    if (tid < 64) {
        const float t1 = red[0][0][tid] + red[0][1][tid] + red[0][2][tid] + red[0][3][tid];
        const float t2 = red[1][0][tid] + red[1][1][tid] + red[1][2][tid] + red[1][3][tid];
        pbuf[tile * 128 + tid] = t1;
        pbuf[tile * 128 + 64 + tid] = t2;
    }
}

// ---------------- reduce LN partials -> scale/shift ----------------
__global__ __launch_bounds__(1024)
void k_norm2(const float* __restrict__ pbuf, const float* __restrict__ g,
             const float* __restrict__ be, float* __restrict__ scale,
             float* __restrict__ shift)
{
    __shared__ float s[1024];
    const int t = threadIdx.x, j = t & 127, gg = t >> 7;
    float a = 0.f;
    for (int b = gg; b < NTILE; b += 8) a += pbuf[b * 128 + j];
    s[t] = a;
    __syncthreads();
    if (t < 128) {
        float tot = 0.f;
#pragma unroll
        for (int k = 0; k < 8; ++k) tot += s[j + 128 * k];
        s[t] = tot;
    }
    __syncthreads();
    if (t < 64) {
        const double mu  = (double)s[t] / (double)N_NODESC;
        const double var = (double)s[64 + t] / (double)N_NODESC - mu * mu;
        const double sc  = (double)g[t] / sqrt(var + (double)EPSF);
        scale[t] = (float)sc;
        shift[t] = (float)((double)be[t] - mu * sc);
    }
}

// ---------------- final projection (LN apply fused) ----------------
__global__ __launch_bounds__(256)
void k_out(const float* __restrict__ outb, const float* __restrict__ scale,
           const float* __restrict__ shift, const float* __restrict__ resW,
           const float* __restrict__ resb, float* __restrict__ out)
{
    const int n = blockIdx.x * 256 + threadIdx.x;
    if (n >= N_NODESC) return;
    float a0 = resb[0], a1 = resb[1];
    const float* __restrict__ r = outb + (long)n * 64;
#pragma unroll 8
    for (int e = 0; e < 64; ++e) {
        const float v = fmaxf(r[e] * scale[e] + shift[e], 0.f);
        a0 += v * resW[2 * e];
        a1 += v * resW[2 * e + 1];
    }
    out[2 * n] = a0;
    out[2 * n + 1] = a1;
}

extern "C" void kernel_launch(void* const* d_in, const int* in_sizes, int n_in,
                              void* d_out, int out_size, void* d_ws, size_t ws_size,
                              hipStream_t stream)
{
    const float* x      = (const float*)d_in[0];
    const float* M      = (const float*)d_in[1];
    const int*   src    = (const int*)d_in[2];
    const int*   dst    = (const int*)d_in[3];
    const int*   labels = (const int*)d_in[4];
    const int*   bidx   = (const int*)d_in[5];
    const float* resW   = (const float*)d_in[18];
    const float* resb   = (const float*)d_in[19];
    float* out = (float*)d_out;

    char* ws = (char*)d_ws;
    float*  scale = (float*)(ws + WS_SCALE);
    float*  shift = (float*)(ws + WS_SHIFT);
    int*    bsum  = (int*)(ws + WS_BSUM);
    float*  pbuf  = (float*)(ws + WS_PBUF);
    int*    hist  = (int*)(ws + WS_HIST);
    int*    fill  = (int*)(ws + WS_FILL);
    int*    seg   = (int*)(ws + WS_SEG);
    int*    elist = (int*)(ws + WS_ELIST);
    ushort* Ahi   = (ushort*)(ws + WS_AHI);
    ushort* Alo   = (ushort*)(ws + WS_ALO);
    ushort* hhi   = (ushort*)(ws + WS_HHI);
    ushort* hlo   = (ushort*)(ws + WS_HLO);
    float*  hB    = (float*)(ws + WS_HB);
    float*  outb  = (float*)(ws + WS_OUTB);

    const int NB64 = (N_NODESC * 64 + 255) / 256;  // 12500

    // ---- preprocessing (graph + M constant across layers) ----
    hipMemsetAsync(hist, 0, 2 * (size_t)NKEYS * sizeof(int), stream);  // hist + fill
    k_hist<<<NEBLK, 256, 0, stream>>>(src, dst, labels, bidx, hist);
    k_bsum<<<NHBLK, 256, 0, stream>>>(hist, bsum);
    k_bscan2<<<1, 1024, 0, stream>>>(bsum);
    k_escan2<<<NHBLK, 256, 0, stream>>>(hist, bsum, seg);
    k_scat<<<NEBLK, 256, 0, stream>>>(src, dst, labels, bidx, seg, fill, elist);
    k_mfrag<<<16, 256, 0, stream>>>(M, Ahi, Alo);

    for (int l = 0; l < 3; ++l) {
        const float* W  = (const float*)d_in[6 + 4 * l];
        const float* b  = (const float*)d_in[7 + 4 * l];
        const float* g  = (const float*)d_in[8 + 4 * l];
        const float* be = (const float*)d_in[9 + 4 * l];

        if (l == 0) {
            k_h<<<NB64, 256, 0, stream>>>(x, W, b, hB, hhi, hlo, 128);
        } else {
            k_happly<<<N_NODESC / 4, 256, 0, stream>>>(outb, scale, shift, W, b,
                                                       hB, hhi, hlo);
        }
        k_msgF<<<NTILE, 256, 0, stream>>>(hhi, hlo, hB, elist, seg, Ahi, Alo,
                                          outb, pbuf);
        k_norm2<<<1, 1024, 0, stream>>>(pbuf, g, be, scale, shift);
    }
    k_out<<<(N_NODESC + 255) / 256, 256, 0, stream>>>(outb, scale, shift, resW, resb, out);
    (void)in_sizes; (void)n_in; (void)out_size; (void)ws_size;
}